// Round 12
// baseline (3789.443 us; speedup 1.0000x reference)
//
#include <hip/hip_runtime.h>
#include <math.h>
#include <stdint.h>

#define B 64
#define S 512
#define DIN 768
#define H 64
#define G4 256   // 4*H gates per direction
#define NG 512   // 2 directions * 4H
#define DM 128   // bidirectional output width

typedef _Float16 h2_t __attribute__((ext_vector_type(2)));
typedef _Float16 f16x8 __attribute__((ext_vector_type(8)));
typedef float f32x4 __attribute__((ext_vector_type(4)));

#if defined(__has_builtin)
#if __has_builtin(__builtin_amdgcn_fdot2)
#define HAS_FDOT2 1
#endif
#endif

__device__ __forceinline__ h2_t u2h(uint32_t u) {
    h2_t h;
    __builtin_memcpy(&h, &u, 4);
    return h;
}

__device__ __forceinline__ float dot2f(h2_t a, h2_t b, float acc) {
#ifdef HAS_FDOT2
    return __builtin_amdgcn_fdot2(a, b, acc, false);
#else
    acc = fmaf((float)a.x, (float)b.x, acc);
    return fmaf((float)a.y, (float)b.y, acc);
#endif
}

__device__ __forceinline__ float sigm(float x) {
    return 1.0f / (1.0f + __expf(-x));
}
__device__ __forceinline__ float tanh_fast(float x) {
    return 1.0f - 2.0f / (__expf(2.0f * x) + 1.0f);
}

// ---------------------------------------------------------------------------
// Pooling: word_ids are sorted per row -> run-length accumulate, no atomics.
// ---------------------------------------------------------------------------
__global__ void pool_kernel(const float* __restrict__ emb,
                            const int* __restrict__ ids,
                            float* __restrict__ merged) {
    int b = blockIdx.x;
    int d = blockIdx.y * 128 + threadIdx.x;
    __shared__ int ids_s[S];
    for (int i = threadIdx.x; i < S; i += blockDim.x) ids_s[i] = ids[b * S + i];
    __syncthreads();
    const float* eb = emb + (size_t)b * S * DIN + d;
    float* mb = merged + (size_t)b * S * DIN + d;
    float acc = 0.f;
    for (int s = 0; s < S; ++s) {
        acc += eb[(size_t)s * DIN];
        int id = ids_s[s];
        bool flush = (s == S - 1) || (ids_s[s + 1] != id);
        if (flush) {
            mb[(size_t)id * DIN] = acc;
            acc = 0.f;
        }
    }
}

// ---------------------------------------------------------------------------
// Mask: one 64-lane wave per (b,word) row; mask = (sum over 768 != 0)
// ---------------------------------------------------------------------------
__global__ void mask_kernel(const float* __restrict__ merged,
                            float* __restrict__ mask) {
    int row = blockIdx.x * 4 + (threadIdx.x >> 6);
    int lane = threadIdx.x & 63;
    const float* r = merged + (size_t)row * DIN;
    float s = 0.f;
    #pragma unroll
    for (int i = 0; i < DIN / 64; ++i) s += r[lane + i * 64];
    #pragma unroll
    for (int off = 32; off > 0; off >>= 1) s += __shfl_down(s, off);
    if (lane == 0) mask[row] = (s != 0.f) ? 1.0f : 0.0f;
}

// ---------------------------------------------------------------------------
// MFMA GEMM: pre[m][dir*256 + j*4 + g] = sum_k A[m][k]*Wt[n][k] + bias[n]
// where n = dir*256 + g*64 + j.  GATE-TRANSPOSED epilogue so the lstm loop
// reads all 4 gate pre-activations of unit j as ONE float4.
// ---------------------------------------------------------------------------
#define LDK 40

__global__ __launch_bounds__(256, 2) void gemm_mfma(
    const float* __restrict__ A, int K,
    const float* __restrict__ Wt, const float* __restrict__ bias,
    float* __restrict__ C) {
    __shared__ __align__(16) _Float16 Alds[128][LDK];
    __shared__ __align__(16) _Float16 Blds[64][LDK];
    int tid = threadIdx.x;
    int lane = tid & 63;
    int wave = tid >> 6;
    int wm = wave >> 1, wn = wave & 1;
    int n0 = blockIdx.x * 64;
    int m0 = blockIdx.y * 128;

    int tr = tid >> 2;            // staging row 0..63
    int tc = (tid & 3) << 3;      // staging k-chunk (8 floats)

    f32x4 acc[4][2] = {};

    const float* Ab = A + (size_t)m0 * K;
    for (int k0 = 0; k0 < K; k0 += 32) {
        {
            const float* src = Ab + (size_t)tr * K + k0 + tc;
            float4 v0 = *(const float4*)(src);
            float4 v1 = *(const float4*)(src + 4);
            _Float16* dst = &Alds[tr][tc];
            dst[0] = (_Float16)v0.x; dst[1] = (_Float16)v0.y;
            dst[2] = (_Float16)v0.z; dst[3] = (_Float16)v0.w;
            dst[4] = (_Float16)v1.x; dst[5] = (_Float16)v1.y;
            dst[6] = (_Float16)v1.z; dst[7] = (_Float16)v1.w;
            src += (size_t)64 * K;
            float4 v2 = *(const float4*)(src);
            float4 v3 = *(const float4*)(src + 4);
            dst = &Alds[tr + 64][tc];
            dst[0] = (_Float16)v2.x; dst[1] = (_Float16)v2.y;
            dst[2] = (_Float16)v2.z; dst[3] = (_Float16)v2.w;
            dst[4] = (_Float16)v3.x; dst[5] = (_Float16)v3.y;
            dst[6] = (_Float16)v3.z; dst[7] = (_Float16)v3.w;
        }
        {
            const float* src = Wt + (size_t)(n0 + tr) * K + k0 + tc;
            float4 v0 = *(const float4*)(src);
            float4 v1 = *(const float4*)(src + 4);
            _Float16* dst = &Blds[tr][tc];
            dst[0] = (_Float16)v0.x; dst[1] = (_Float16)v0.y;
            dst[2] = (_Float16)v0.z; dst[3] = (_Float16)v0.w;
            dst[4] = (_Float16)v1.x; dst[5] = (_Float16)v1.y;
            dst[6] = (_Float16)v1.z; dst[7] = (_Float16)v1.w;
        }
        __syncthreads();

        int fr = lane & 15;
        int kg = (lane >> 4) << 3;
        f16x8 af[4], bf[2];
        #pragma unroll
        for (int mf = 0; mf < 4; ++mf)
            af[mf] = *(const f16x8*)&Alds[wm * 64 + mf * 16 + fr][kg];
        #pragma unroll
        for (int nf = 0; nf < 2; ++nf)
            bf[nf] = *(const f16x8*)&Blds[wn * 32 + nf * 16 + fr][kg];
        #pragma unroll
        for (int mf = 0; mf < 4; ++mf)
            #pragma unroll
            for (int nf = 0; nf < 2; ++nf)
                acc[mf][nf] = __builtin_amdgcn_mfma_f32_16x16x32_f16(
                    af[mf], bf[nf], acc[mf][nf], 0, 0, 0);
        __syncthreads();
    }

    int col = lane & 15;
    int r4 = (lane >> 4) << 2;
    #pragma unroll
    for (int nf = 0; nf < 2; ++nf) {
        int n = n0 + wn * 32 + nf * 16 + col;
        float bv = bias[n];
        int dirn = n >> 8;
        int gg = (n >> 6) & 3;
        int jj = n & 63;
        size_t noff = (size_t)dirn * 256 + jj * 4 + gg;
        #pragma unroll
        for (int mf = 0; mf < 4; ++mf) {
            #pragma unroll
            for (int reg = 0; reg < 4; ++reg) {
                int m = m0 + wm * 64 + mf * 16 + r4 + reg;
                C[(size_t)m * NG + noff] = acc[mf][nf][reg] + bv;
            }
        }
    }
}

// ---------------------------------------------------------------------------
// Recurrence: ONE WAVE per (batch, direction), zero barriers, R7 dot2 core.
// Serial loop stripped to ONE global op (float4 pre prefetch): h-history
// goes to LDS (hh[513][64] f16); xout store + residual add moved to a
// coalesced bulk pass after the loop. Tests the vmcnt-FIFO-interference
// theory (stores + scattered loads in the loop inject serial stalls).
// ---------------------------------------------------------------------------
__global__ __launch_bounds__(64, 1) void lstm_rec(
    const float* __restrict__ pre,   // [B*S][512] gate-transposed
    const float* __restrict__ Whh,   // [512][64] (dir*256+g rows)
    const float* __restrict__ xin,   // [B*S][128] or nullptr
    float* __restrict__ xout,        // [B*S][128]
    int residual) {
    int b = blockIdx.x >> 1;
    int dir = blockIdx.x & 1;
    int j = threadIdx.x & 63;

    h2_t wg0[32], wg1[32], wg2[32], wg3[32];
    {
        const float* w0 = Whh + (size_t)(dir * G4 + 0 * H + j) * H;
        const float* w1 = Whh + (size_t)(dir * G4 + 1 * H + j) * H;
        const float* w2 = Whh + (size_t)(dir * G4 + 2 * H + j) * H;
        const float* w3 = Whh + (size_t)(dir * G4 + 3 * H + j) * H;
        #pragma unroll
        for (int kk = 0; kk < 32; ++kk) {
            float2 v;
            h2_t p;
            v = *(const float2*)&w0[kk * 2];
            p.x = (_Float16)v.x; p.y = (_Float16)v.y; wg0[kk] = p;
            v = *(const float2*)&w1[kk * 2];
            p.x = (_Float16)v.x; p.y = (_Float16)v.y; wg1[kk] = p;
            v = *(const float2*)&w2[kk * 2];
            p.x = (_Float16)v.x; p.y = (_Float16)v.y; wg2[kk] = p;
            v = *(const float2*)&w3[kk * 2];
            p.x = (_Float16)v.x; p.y = (_Float16)v.y; wg3[kk] = p;
        }
    }

    // pre: one float4 per step at [m][dir*256 + j*4]
    const float* preb = pre + dir * G4 + j * 4;
    size_t mbase = (size_t)b * S;

    float4 pbuf[4];
    #pragma unroll
    for (int i = 0; i < 4; ++i) {
        int s = dir ? (S - 1 - i) : i;
        pbuf[i] = *(const float4*)(preb + (mbase + s) * NG);
    }

    // h history: hh[t+1] = h(t); row 0 = h(-1) = 0.  513*128B = 65.7KB
    __shared__ __align__(16) _Float16 hh[513][64];
    hh[0][j] = (_Float16)0.f;

    float c = 0.f;
    #pragma unroll 4
    for (int step = 0; step < S; ++step) {
        int q = step & 3;

        // ---- broadcast-read h(step-1) = hh[step] (8 x ds_read_b128)
        uint4 hq[8];
        const uint4* hp = (const uint4*)&hh[step][0];
        #pragma unroll
        for (int r = 0; r < 8; ++r) hq[r] = hp[r];

        float4 p4 = pbuf[q];
        int sn = step + 4;
        if (sn < S) {
            int s2 = dir ? (S - 1 - sn) : sn;
            pbuf[q] = *(const float4*)(preb + (mbase + s2) * NG);
        }

        // ---- dots (R7 core: dot2, even/odd accumulators)
        float ai0 = p4.x, af0 = p4.y, ag0 = p4.z, ao0 = p4.w;
        float ai1 = 0.f, af1 = 0.f, ag1 = 0.f, ao1 = 0.f;
        #pragma unroll
        for (int r = 0; r < 8; ++r) {
            uint32_t uu[4] = {hq[r].x, hq[r].y, hq[r].z, hq[r].w};
            #pragma unroll
            for (int cc = 0; cc < 4; ++cc) {
                int kk = r * 4 + cc;
                h2_t hhv = u2h(uu[cc]);
                if (kk & 1) {
                    ai1 = dot2f(hhv, wg0[kk], ai1);
                    af1 = dot2f(hhv, wg1[kk], af1);
                    ag1 = dot2f(hhv, wg2[kk], ag1);
                    ao1 = dot2f(hhv, wg3[kk], ao1);
                } else {
                    ai0 = dot2f(hhv, wg0[kk], ai0);
                    af0 = dot2f(hhv, wg1[kk], af0);
                    ag0 = dot2f(hhv, wg2[kk], ag0);
                    ao0 = dot2f(hhv, wg3[kk], ao0);
                }
            }
        }
        float ai = ai0 + ai1, af = af0 + af1;
        float ag = ag0 + ag1, ao = ao0 + ao1;

        // ---- activations
        c = sigm(af) * c + sigm(ai) * tanh_fast(ag);
        float h = sigm(ao) * tanh_fast(c);

        // ---- publish h (read at top of next step; same-wave DS ordering)
        hh[step + 1][j] = (_Float16)h;
    }

    // ---- bulk write: xout[s] = h(t(s)) + residual (coalesced, off the
    //      serial path entirely)
    const float* xinb = xin + (size_t)b * S * DM + dir * H + j;
    float* xoutb = xout + (size_t)b * S * DM + dir * H + j;
    for (int st = 0; st < S; ++st) {
        int s = dir ? (S - 1 - st) : st;
        float h = (float)hh[st + 1][j];
        float rv = residual ? xinb[(size_t)s * DM] : 0.f;
        xoutb[(size_t)s * DM] = h + rv;
    }
}

// ---------------------------------------------------------------------------
// Assemble: out0[b,s,0:128] = x, out0[b,s,128] = sn_word_len[b,s]
// ---------------------------------------------------------------------------
__global__ void assemble_kernel(const float* __restrict__ x,
                                const float* __restrict__ wl,
                                float* __restrict__ out0) {
    int idx = blockIdx.x * blockDim.x + threadIdx.x;
    if (idx >= B * S * 129) return;
    int c = idx % 129;
    int bs = idx / 129;
    out0[idx] = (c < 128) ? x[(size_t)bs * DM + c] : wl[bs];
}

extern "C" void kernel_launch(void* const* d_in, const int* in_sizes, int n_in,
                              void* d_out, int out_size, void* d_ws, size_t ws_size,
                              hipStream_t stream) {
    const float* emb  = (const float*)d_in[0];
    const float* wl   = (const float*)d_in[1];
    const float* Wih1 = (const float*)d_in[2];  // [512][768]
    const float* Whh1 = (const float*)d_in[3];  // [512][64]
    const float* b1   = (const float*)d_in[4];  // [512]
    const float* Wih  = (const float*)d_in[5];  // [7][512][128]
    const float* Whh  = (const float*)d_in[6];  // [7][512][64]
    const float* bb   = (const float*)d_in[7];  // [7][512]
    const int*   ids  = (const int*)d_in[8];

    float* out0 = (float*)d_out;
    float* mask_out = out0 + (size_t)B * S * 129;

    float* merged = (float*)d_ws;                       // 25165824 f
    float* pre    = merged + (size_t)B * S * DIN;       // 16777216 f
    float* xA     = pre + (size_t)B * S * NG;           //  4194304 f
    float* xB     = xA + (size_t)B * S * DM;            //  4194304 f

    hipMemsetAsync(merged, 0, (size_t)B * S * DIN * sizeof(float), stream);
    pool_kernel<<<dim3(B, 6), 128, 0, stream>>>(emb, ids, merged);
    mask_kernel<<<(B * S) / 4, 256, 0, stream>>>(merged, mask_out);

    dim3 ggrid(NG / 64, (B * S) / 128);   // (8, 256), N fastest

    // layer 1: 768 -> 128
    gemm_mfma<<<ggrid, 256, 0, stream>>>(merged, DIN, Wih1, b1, pre);
    lstm_rec<<<2 * B, 64, 0, stream>>>(pre, Whh1, nullptr, xA, 0);

    // layer 2: no residual
    gemm_mfma<<<ggrid, 256, 0, stream>>>(xA, DM, Wih, bb, pre);
    lstm_rec<<<2 * B, 64, 0, stream>>>(pre, Whh, nullptr, xB, 0);

    // layers 3..8: residual
    float* cur = xB;
    float* oth = xA;
    for (int l = 1; l < 7; ++l) {
        gemm_mfma<<<ggrid, 256, 0, stream>>>(cur, DM, Wih + (size_t)l * NG * DM,
                                             bb + (size_t)l * NG, pre);
        lstm_rec<<<2 * B, 64, 0, stream>>>(pre, Whh + (size_t)l * NG * H,
                                           cur, oth, 1);
        float* tmp = cur; cur = oth; oth = tmp;
    }
    // cur == xB after 6 swaps

    assemble_kernel<<<(B * S * 129 + 255) / 256, 256, 0, stream>>>(cur, wl, out0);
}

// Round 13
// 3082.793 us; speedup vs baseline: 1.2292x; 1.2292x over previous
//
#include <hip/hip_runtime.h>
#include <math.h>
#include <stdint.h>

#define B 64
#define S 512
#define DIN 768
#define H 64
#define G4 256   // 4*H gates per direction
#define NG 512   // 2 directions * 4H
#define DM 128   // bidirectional output width

typedef _Float16 h2_t __attribute__((ext_vector_type(2)));
typedef _Float16 f16x8 __attribute__((ext_vector_type(8)));
typedef float f32x4 __attribute__((ext_vector_type(4)));

#if defined(__has_builtin)
#if __has_builtin(__builtin_amdgcn_fdot2)
#define HAS_FDOT2 1
#endif
#if __has_builtin(__builtin_amdgcn_rcpf)
#define RCPF(x) __builtin_amdgcn_rcpf(x)
#endif
#endif
#ifndef RCPF
#define RCPF(x) (1.0f / (x))
#endif

__device__ __forceinline__ h2_t u2h(uint32_t u) {
    h2_t h;
    __builtin_memcpy(&h, &u, 4);
    return h;
}

__device__ __forceinline__ float dot2f(h2_t a, h2_t b, float acc) {
#ifdef HAS_FDOT2
    return __builtin_amdgcn_fdot2(a, b, acc, false);
#else
    acc = fmaf((float)a.x, (float)b.x, acc);
    return fmaf((float)a.y, (float)b.y, acc);
#endif
}

// v_rcp_f32-based activations: without -ffast-math, 1.0f/x expands to the
// IEEE div sequence (~10 instrs, ~40cy) -- 5 of them per lstm step was a
// large hidden serial cost. v_rcp is 1 instr, ~1ulp.
__device__ __forceinline__ float sigm(float x) {
    return RCPF(1.0f + __expf(-x));
}
__device__ __forceinline__ float tanh_fast(float x) {
    // tanh(x) = 1 - 2/(exp(2x)+1)
    return fmaf(-2.0f, RCPF(__expf(2.0f * x) + 1.0f), 1.0f);
}

// ---------------------------------------------------------------------------
// Pooling: word_ids are sorted per row -> run-length accumulate, no atomics.
// FUSED MASK: word w has >=1 subword  <=>  rowsum != 0 (random normal data),
// so one lane writes mask=1 at each flush. mask must be pre-zeroed.
// ---------------------------------------------------------------------------
__global__ void pool_kernel(const float* __restrict__ emb,
                            const int* __restrict__ ids,
                            float* __restrict__ merged,
                            float* __restrict__ mask) {
    int b = blockIdx.x;
    int d = blockIdx.y * 128 + threadIdx.x;
    __shared__ int ids_s[S];
    for (int i = threadIdx.x; i < S; i += blockDim.x) ids_s[i] = ids[b * S + i];
    __syncthreads();
    const float* eb = emb + (size_t)b * S * DIN + d;
    float* mb = merged + (size_t)b * S * DIN + d;
    float acc = 0.f;
    for (int s = 0; s < S; ++s) {
        acc += eb[(size_t)s * DIN];
        int id = ids_s[s];
        bool flush = (s == S - 1) || (ids_s[s + 1] != id);
        if (flush) {
            mb[(size_t)id * DIN] = acc;
            acc = 0.f;
            if (blockIdx.y == 0 && threadIdx.x == 0)
                mask[b * S + id] = 1.0f;
        }
    }
}

// ---------------------------------------------------------------------------
// MFMA GEMM: C[m][n] = sum_k A[m][k]*Wt[n][k] + bias[n], via f16 MFMA.
// (Round-6 version, standard [m][n] epilogue.)
// ---------------------------------------------------------------------------
#define LDK 40

__global__ __launch_bounds__(256, 2) void gemm_mfma(
    const float* __restrict__ A, int K,
    const float* __restrict__ Wt, const float* __restrict__ bias,
    float* __restrict__ C) {
    __shared__ __align__(16) _Float16 Alds[128][LDK];
    __shared__ __align__(16) _Float16 Blds[64][LDK];
    int tid = threadIdx.x;
    int lane = tid & 63;
    int wave = tid >> 6;
    int wm = wave >> 1, wn = wave & 1;
    int n0 = blockIdx.x * 64;
    int m0 = blockIdx.y * 128;

    int tr = tid >> 2;            // staging row 0..63
    int tc = (tid & 3) << 3;      // staging k-chunk (8 floats)

    f32x4 acc[4][2] = {};

    const float* Ab = A + (size_t)m0 * K;
    for (int k0 = 0; k0 < K; k0 += 32) {
        {
            const float* src = Ab + (size_t)tr * K + k0 + tc;
            float4 v0 = *(const float4*)(src);
            float4 v1 = *(const float4*)(src + 4);
            _Float16* dst = &Alds[tr][tc];
            dst[0] = (_Float16)v0.x; dst[1] = (_Float16)v0.y;
            dst[2] = (_Float16)v0.z; dst[3] = (_Float16)v0.w;
            dst[4] = (_Float16)v1.x; dst[5] = (_Float16)v1.y;
            dst[6] = (_Float16)v1.z; dst[7] = (_Float16)v1.w;
            src += (size_t)64 * K;
            float4 v2 = *(const float4*)(src);
            float4 v3 = *(const float4*)(src + 4);
            dst = &Alds[tr + 64][tc];
            dst[0] = (_Float16)v2.x; dst[1] = (_Float16)v2.y;
            dst[2] = (_Float16)v2.z; dst[3] = (_Float16)v2.w;
            dst[4] = (_Float16)v3.x; dst[5] = (_Float16)v3.y;
            dst[6] = (_Float16)v3.z; dst[7] = (_Float16)v3.w;
        }
        {
            const float* src = Wt + (size_t)(n0 + tr) * K + k0 + tc;
            float4 v0 = *(const float4*)(src);
            float4 v1 = *(const float4*)(src + 4);
            _Float16* dst = &Blds[tr][tc];
            dst[0] = (_Float16)v0.x; dst[1] = (_Float16)v0.y;
            dst[2] = (_Float16)v0.z; dst[3] = (_Float16)v0.w;
            dst[4] = (_Float16)v1.x; dst[5] = (_Float16)v1.y;
            dst[6] = (_Float16)v1.z; dst[7] = (_Float16)v1.w;
        }
        __syncthreads();

        int fr = lane & 15;
        int kg = (lane >> 4) << 3;
        f16x8 af[4], bf[2];
        #pragma unroll
        for (int mf = 0; mf < 4; ++mf)
            af[mf] = *(const f16x8*)&Alds[wm * 64 + mf * 16 + fr][kg];
        #pragma unroll
        for (int nf = 0; nf < 2; ++nf)
            bf[nf] = *(const f16x8*)&Blds[wn * 32 + nf * 16 + fr][kg];
        #pragma unroll
        for (int mf = 0; mf < 4; ++mf)
            #pragma unroll
            for (int nf = 0; nf < 2; ++nf)
                acc[mf][nf] = __builtin_amdgcn_mfma_f32_16x16x32_f16(
                    af[mf], bf[nf], acc[mf][nf], 0, 0, 0);
        __syncthreads();
    }

    int col = lane & 15;
    int r4 = (lane >> 4) << 2;
    #pragma unroll
    for (int nf = 0; nf < 2; ++nf) {
        int n = n0 + wn * 32 + nf * 16 + col;
        float bv = bias[n];
        #pragma unroll
        for (int mf = 0; mf < 4; ++mf) {
            #pragma unroll
            for (int reg = 0; reg < 4; ++reg) {
                int m = m0 + wm * 64 + mf * 16 + r4 + reg;
                C[(size_t)m * NG + n] = acc[mf][nf][reg] + bv;
            }
        }
    }
}

// ---------------------------------------------------------------------------
// Recurrence: ONE WAVE per (batch, direction). Zero barriers. EXACT Round-6
// structure (the 263us local optimum: broadcast reads at top, single
// accumulator per gate, scalar pre loads, fixed LDS addrs, store at bottom).
// Only change vs Round-6: rcp-based activations (see sigm/tanh_fast above).
// ---------------------------------------------------------------------------
__global__ __launch_bounds__(64, 1) void lstm_rec(
    const float* __restrict__ pre,   // [B*S][512]
    const float* __restrict__ Whh,   // [512][64] (dir*256+g rows)
    const float* __restrict__ xin,   // [B*S][128] or nullptr
    float* __restrict__ xout,        // [B*S][128]
    int residual) {
    int b = blockIdx.x >> 1;
    int dir = blockIdx.x & 1;
    int j = threadIdx.x & 63;

    h2_t wg0[32], wg1[32], wg2[32], wg3[32];
    {
        const float* w0 = Whh + (size_t)(dir * G4 + 0 * H + j) * H;
        const float* w1 = Whh + (size_t)(dir * G4 + 1 * H + j) * H;
        const float* w2 = Whh + (size_t)(dir * G4 + 2 * H + j) * H;
        const float* w3 = Whh + (size_t)(dir * G4 + 3 * H + j) * H;
        #pragma unroll
        for (int kk = 0; kk < 32; ++kk) {
            float2 v;
            h2_t p;
            v = *(const float2*)&w0[kk * 2];
            p.x = (_Float16)v.x; p.y = (_Float16)v.y; wg0[kk] = p;
            v = *(const float2*)&w1[kk * 2];
            p.x = (_Float16)v.x; p.y = (_Float16)v.y; wg1[kk] = p;
            v = *(const float2*)&w2[kk * 2];
            p.x = (_Float16)v.x; p.y = (_Float16)v.y; wg2[kk] = p;
            v = *(const float2*)&w3[kk * 2];
            p.x = (_Float16)v.x; p.y = (_Float16)v.y; wg3[kk] = p;
        }
    }

    const float* preb = pre + (size_t)b * S * NG + dir * G4 + j;
    const float* xinb = xin + (size_t)b * S * DM + dir * H + j;
    float* xoutb = xout + (size_t)b * S * DM + dir * H + j;

    float pi[4], pf[4], pg_[4], po[4], rb[4] = {0.f, 0.f, 0.f, 0.f};
    #pragma unroll
    for (int i = 0; i < 4; ++i) {
        int s = dir ? (S - 1 - i) : i;
        const float* p = preb + (size_t)s * NG;
        pi[i] = p[0];
        pf[i] = p[64];
        pg_[i] = p[128];
        po[i] = p[192];
        if (residual) rb[i] = xinb[(size_t)s * DM];
    }

    __shared__ __align__(16) _Float16 shh[64];
    shh[j] = (_Float16)0.f;

    float c = 0.f;
    #pragma unroll 4
    for (int step = 0; step < S; ++step) {
        int s = dir ? (S - 1 - step) : step;
        int q = step & 3;
        float rv = rb[q];

        // ---- broadcast-read all 64 h values (8 x ds_read_b128, uniform)
        uint4 hq[8];
        const uint4* hp = (const uint4*)shh;
        #pragma unroll
        for (int r = 0; r < 8; ++r) hq[r] = hp[r];

        // ---- dots (single accumulator per gate, 4 interleaved chains)
        float ai = pi[q], af = pf[q], ag = pg_[q], ao = po[q];
        #pragma unroll
        for (int r = 0; r < 8; ++r) {
            uint32_t uu[4] = {hq[r].x, hq[r].y, hq[r].z, hq[r].w};
            #pragma unroll
            for (int cc = 0; cc < 4; ++cc) {
                int kk = r * 4 + cc;
                h2_t hh = u2h(uu[cc]);
                ai = dot2f(hh, wg0[kk], ai);
                af = dot2f(hh, wg1[kk], af);
                ag = dot2f(hh, wg2[kk], ag);
                ao = dot2f(hh, wg3[kk], ao);
            }
        }

        // ---- activations (rcp-based, short serial chain)
        c = sigm(af) * c + sigm(ai) * tanh_fast(ag);
        float h = sigm(ao) * tanh_fast(c);

        // ---- publish h (read at top of next step; same-wave DS ordering)
        shh[j] = (_Float16)h;

        // ---- store + prefetch tail
        int sn = step + 4;
        if (sn < S) {
            int s2 = dir ? (S - 1 - sn) : sn;
            const float* p = preb + (size_t)s2 * NG;
            pi[q] = p[0];
            pf[q] = p[64];
            pg_[q] = p[128];
            po[q] = p[192];
            if (residual) rb[q] = xinb[(size_t)s2 * DM];
        }
        xoutb[(size_t)s * DM] = h + rv;
    }
}

// ---------------------------------------------------------------------------
// Assemble: out0[b,s,0:128] = x, out0[b,s,128] = sn_word_len[b,s]
// ---------------------------------------------------------------------------
__global__ void assemble_kernel(const float* __restrict__ x,
                                const float* __restrict__ wl,
                                float* __restrict__ out0) {
    int idx = blockIdx.x * blockDim.x + threadIdx.x;
    if (idx >= B * S * 129) return;
    int c = idx % 129;
    int bs = idx / 129;
    out0[idx] = (c < 128) ? x[(size_t)bs * DM + c] : wl[bs];
}

extern "C" void kernel_launch(void* const* d_in, const int* in_sizes, int n_in,
                              void* d_out, int out_size, void* d_ws, size_t ws_size,
                              hipStream_t stream) {
    const float* emb  = (const float*)d_in[0];
    const float* wl   = (const float*)d_in[1];
    const float* Wih1 = (const float*)d_in[2];  // [512][768]
    const float* Whh1 = (const float*)d_in[3];  // [512][64]
    const float* b1   = (const float*)d_in[4];  // [512]
    const float* Wih  = (const float*)d_in[5];  // [7][512][128]
    const float* Whh  = (const float*)d_in[6];  // [7][512][64]
    const float* bb   = (const float*)d_in[7];  // [7][512]
    const int*   ids  = (const int*)d_in[8];

    float* out0 = (float*)d_out;
    float* mask_out = out0 + (size_t)B * S * 129;

    float* merged = (float*)d_ws;                       // 25165824 f
    float* pre    = merged + (size_t)B * S * DIN;       // 16777216 f
    float* xA     = pre + (size_t)B * S * NG;           //  4194304 f
    float* xB     = xA + (size_t)B * S * DM;            //  4194304 f

    hipMemsetAsync(merged, 0, (size_t)B * S * DIN * sizeof(float), stream);
    hipMemsetAsync(mask_out, 0, (size_t)B * S * sizeof(float), stream);
    pool_kernel<<<dim3(B, 6), 128, 0, stream>>>(emb, ids, merged, mask_out);

    dim3 ggrid(NG / 64, (B * S) / 128);   // (8, 256), N fastest

    // layer 1: 768 -> 128
    gemm_mfma<<<ggrid, 256, 0, stream>>>(merged, DIN, Wih1, b1, pre);
    lstm_rec<<<2 * B, 64, 0, stream>>>(pre, Whh1, nullptr, xA, 0);

    // layer 2: no residual
    gemm_mfma<<<ggrid, 256, 0, stream>>>(xA, DM, Wih, bb, pre);
    lstm_rec<<<2 * B, 64, 0, stream>>>(pre, Whh, nullptr, xB, 0);

    // layers 3..8: residual
    float* cur = xB;
    float* oth = xA;
    for (int l = 1; l < 7; ++l) {
        gemm_mfma<<<ggrid, 256, 0, stream>>>(cur, DM, Wih + (size_t)l * NG * DM,
                                             bb + (size_t)l * NG, pre);
        lstm_rec<<<2 * B, 64, 0, stream>>>(pre, Whh + (size_t)l * NG * H,
                                           cur, oth, 1);
        float* tmp = cur; cur = oth; oth = tmp;
    }
    // cur == xB after 6 swaps

    assemble_kernel<<<(B * S * 129 + 255) / 256, 256, 0, stream>>>(cur, wl, out0);
}